// Round 1
// baseline (901.669 us; speedup 1.0000x reference)
//
#include <hip/hip_runtime.h>
#include <hip/hip_bf16.h>

#define NN 50000
#define NE 1000000
#define DIM 64
#define NG 256

// h = X @ W   (X: [nrows,64], W: [64,64] row-major)
// one wave per row; W staged in LDS; row broadcast via shfl.
__global__ void gemm64_kernel(const float* __restrict__ X, const float* __restrict__ W,
                              float* __restrict__ H, int nrows) {
    __shared__ float Wl[64 * 64];
    int tid = threadIdx.x;
    for (int i = tid; i < 64 * 64; i += blockDim.x) Wl[i] = W[i];
    __syncthreads();
    int lane = tid & 63;
    int gw = (blockIdx.x * blockDim.x + tid) >> 6;
    int nw = (gridDim.x * blockDim.x) >> 6;
    for (int row = gw; row < nrows; row += nw) {
        float xv = X[(size_t)row * 64 + lane];
        float acc = 0.f;
#pragma unroll
        for (int k = 0; k < 64; ++k)
            acc = fmaf(__shfl(xv, k, 64), Wl[k * 64 + lane], acc);
        H[(size_t)row * 64 + lane] = acc;
    }
}

// AGG[dst[e]][c] += H[src[e]][c]  for all edges; one wave per edge.
__global__ void scatter_kernel(const float* __restrict__ H, const int* __restrict__ src,
                               const int* __restrict__ dst, float* __restrict__ AGG) {
    int tid = blockIdx.x * blockDim.x + threadIdx.x;
    int lane = tid & 63;
    int gw = tid >> 6;
    int nw = (gridDim.x * blockDim.x) >> 6;
    for (int e = gw; e < NE; e += nw) {
        int s = src[e];
        int d = dst[e];
        float v = H[(size_t)s * 64 + lane];
        unsafeAtomicAdd(&AGG[(size_t)d * 64 + lane], v);
    }
}

// In-place ReLU on X (becomes layer output), plus per-graph add-pool.
// batch is sorted: each wave takes a contiguous chunk of nodes and
// accumulates in registers, flushing one atomic per graph transition.
__global__ void relupool_kernel(float* __restrict__ X, const int* __restrict__ batch,
                                float* __restrict__ pool) {
    int tid = blockIdx.x * blockDim.x + threadIdx.x;
    int lane = tid & 63;
    int gw = tid >> 6;
    int nw = (gridDim.x * blockDim.x) >> 6;
    int chunk = (NN + nw - 1) / nw;
    int start = gw * chunk;
    if (start >= NN) return;
    int end = min(start + chunk, NN);
    float acc = 0.f;
    int curg = batch[start];
    for (int node = start; node < end; ++node) {
        float v = fmaxf(X[(size_t)node * 64 + lane], 0.f);
        X[(size_t)node * 64 + lane] = v;
        int g = batch[node];
        if (g != curg) {                       // wave-uniform branch
            unsafeAtomicAdd(&pool[(size_t)curg * 64 + lane], acc);
            acc = 0.f;
            curg = g;
        }
        acc += v;
    }
    unsafeAtomicAdd(&pool[(size_t)curg * 64 + lane], acc);
}

// out[g][c] = relu( sum_l  pool_l[g] . Wp_l[:,c] )
__global__ void final_kernel(const float* __restrict__ P1, const float* __restrict__ P2,
                             const float* __restrict__ P3,
                             const float* __restrict__ Wp1, const float* __restrict__ Wp2,
                             const float* __restrict__ Wp3, float* __restrict__ out) {
    int g = blockIdx.x;
    int c = threadIdx.x;  // 64 threads
    float acc = 0.f;
#pragma unroll
    for (int k = 0; k < 64; ++k) {
        acc = fmaf(P1[g * 64 + k], Wp1[k * 64 + c], acc);
        acc = fmaf(P2[g * 64 + k], Wp2[k * 64 + c], acc);
        acc = fmaf(P3[g * 64 + k], Wp3[k * 64 + c], acc);
    }
    out[g * 64 + c] = fmaxf(acc, 0.f);
}

extern "C" void kernel_launch(void* const* d_in, const int* in_sizes, int n_in,
                              void* d_out, int out_size, void* d_ws, size_t ws_size,
                              hipStream_t stream) {
    const float* x    = (const float*)d_in[0];
    const int*   eidx = (const int*)d_in[1];   // [2, NE] int
    const int*   batch= (const int*)d_in[2];   // [NN] int (sorted)
    const float* W1   = (const float*)d_in[3];
    const float* W2   = (const float*)d_in[4];
    const float* W3   = (const float*)d_in[5];
    const float* Wp1  = (const float*)d_in[6];
    const float* Wp2  = (const float*)d_in[7];
    const float* Wp3  = (const float*)d_in[8];
    float* out = (float*)d_out;

    const int* src = eidx;
    const int* dst = eidx + NE;

    float* bufA  = (float*)d_ws;                      // h        (12.8 MB)
    float* bufB  = bufA + (size_t)NN * DIM;           // agg / x  (12.8 MB)
    float* pool1 = bufB + (size_t)NN * DIM;
    float* pool2 = pool1 + (size_t)NG * DIM;
    float* pool3 = pool2 + (size_t)NG * DIM;

    hipMemsetAsync(pool1, 0, (size_t)3 * NG * DIM * sizeof(float), stream);

    dim3 blk(256);
    const int gemm_blocks = 1024;  // 4096 waves, grid-stride over 50000 rows
    const int scat_blocks = 2048;  // 8192 waves, grid-stride over 1M edges
    const int pool_blocks = 512;   // 2048 waves, chunk ~= 25 nodes each

    const float* xin = x;
    const float* Ws[3]  = {W1, W2, W3};
    float* pools[3] = {pool1, pool2, pool3};
    for (int l = 0; l < 3; ++l) {
        gemm64_kernel<<<gemm_blocks, blk, 0, stream>>>(xin, Ws[l], bufA, NN);
        hipMemsetAsync(bufB, 0, (size_t)NN * DIM * sizeof(float), stream);
        scatter_kernel<<<scat_blocks, blk, 0, stream>>>(bufA, src, dst, bufB);
        relupool_kernel<<<pool_blocks, blk, 0, stream>>>(bufB, batch, pools[l]);
        xin = bufB;
    }
    final_kernel<<<NG, 64, 0, stream>>>(pool1, pool2, pool3, Wp1, Wp2, Wp3, out);
}

// Round 3
// 450.036 us; speedup vs baseline: 2.0035x; 2.0035x over previous
//
#include <hip/hip_runtime.h>
#include <hip/hip_bf16.h>

#define NN 50000
#define NE 1000000
#define DIM 64
#define NG 256
#define NB_SCAN 196   // ceil(NN/256)

// ---------- CSR build (counting sort of edges by dst) ----------
__global__ void hist_kernel(const int* __restrict__ dst, int* __restrict__ count) {
    int i = blockIdx.x * blockDim.x + threadIdx.x;
    int stride = gridDim.x * blockDim.x;
    for (int e = i; e < NE; e += stride) atomicAdd(&count[dst[e]], 1);
}

__global__ void scanA_kernel(const int* __restrict__ count, int* __restrict__ blocksum) {
    __shared__ int tmp[256];
    int t = threadIdx.x;
    int i = blockIdx.x * 256 + t;
    tmp[t] = (i < NN) ? count[i] : 0;
    __syncthreads();
    for (int s = 128; s > 0; s >>= 1) {
        if (t < s) tmp[t] += tmp[t + s];
        __syncthreads();
    }
    if (t == 0) blocksum[blockIdx.x] = tmp[0];
}

__global__ void scanB_kernel(int* __restrict__ blocksum) {  // exclusive scan, in place
    __shared__ int tmp[256];
    int t = threadIdx.x;
    int v = (t < NB_SCAN) ? blocksum[t] : 0;
    tmp[t] = v;
    __syncthreads();
    for (int off = 1; off < 256; off <<= 1) {
        int a = (t >= off) ? tmp[t - off] : 0;
        __syncthreads();
        tmp[t] += a;
        __syncthreads();
    }
    if (t < NB_SCAN) blocksum[t] = tmp[t] - v;
}

__global__ void scanC_kernel(const int* __restrict__ count, const int* __restrict__ blocksum,
                             int* __restrict__ offsets, int* __restrict__ cursor) {
    __shared__ int tmp[256];
    int t = threadIdx.x;
    int i = blockIdx.x * 256 + t;
    int v = (i < NN) ? count[i] : 0;
    tmp[t] = v;
    __syncthreads();
    for (int off = 1; off < 256; off <<= 1) {
        int a = (t >= off) ? tmp[t - off] : 0;
        __syncthreads();
        tmp[t] += a;
        __syncthreads();
    }
    int excl = tmp[t] - v + blocksum[blockIdx.x];
    if (i < NN) { offsets[i] = excl; cursor[i] = excl; }
    if (i == 0) offsets[NN] = NE;
}

__global__ void fill_kernel(const int* __restrict__ src, const int* __restrict__ dst,
                            int* __restrict__ cursor, int* __restrict__ csr) {
    int i = blockIdx.x * blockDim.x + threadIdx.x;
    int stride = gridDim.x * blockDim.x;
    for (int e = i; e < NE; e += stride) {
        int d = dst[e];
        int pos = atomicAdd(&cursor[d], 1);
        csr[pos] = src[e];
    }
}

// ---------- H = X @ W : thread-per-row, W via wave-uniform (scalar) loads ----------
__global__ __launch_bounds__(128) void gemm64_kernel(const float* __restrict__ X,
                                                     const float* __restrict__ W,
                                                     float* __restrict__ H, int nrows) {
    __shared__ float Xl[128 * 65];   // +1 pad: bank = (row+k)%32 -> 2-way alias (free)
    int t = threadIdx.x;
    int base = blockIdx.x * 128;
    for (int idx = t; idx < 128 * 16; idx += 128) {
        int row = idx >> 4;
        int c4  = idx & 15;
        float4 v = make_float4(0.f, 0.f, 0.f, 0.f);
        if (base + row < nrows)
            v = *reinterpret_cast<const float4*>(&X[(size_t)(base + row) * 64 + c4 * 4]);
        float* p = &Xl[row * 65 + c4 * 4];
        p[0] = v.x; p[1] = v.y; p[2] = v.z; p[3] = v.w;
    }
    __syncthreads();
    float acc[64];
#pragma unroll
    for (int c = 0; c < 64; ++c) acc[c] = 0.f;
#pragma unroll 4
    for (int k = 0; k < 64; ++k) {
        float xv = Xl[t * 65 + k];
#pragma unroll
        for (int c4 = 0; c4 < 16; ++c4) {
            float4 w = *reinterpret_cast<const float4*>(&W[k * 64 + c4 * 4]); // uniform -> s_load
            acc[c4 * 4 + 0] = fmaf(xv, w.x, acc[c4 * 4 + 0]);
            acc[c4 * 4 + 1] = fmaf(xv, w.y, acc[c4 * 4 + 1]);
            acc[c4 * 4 + 2] = fmaf(xv, w.z, acc[c4 * 4 + 2]);
            acc[c4 * 4 + 3] = fmaf(xv, w.w, acc[c4 * 4 + 3]);
        }
    }
    int row = base + t;
    if (row < nrows) {
#pragma unroll
        for (int c4 = 0; c4 < 16; ++c4) {
            float4 o = make_float4(acc[c4 * 4 + 0], acc[c4 * 4 + 1],
                                   acc[c4 * 4 + 2], acc[c4 * 4 + 3]);
            *reinterpret_cast<float4*>(&H[(size_t)row * 64 + c4 * 4]) = o;
        }
    }
}

// ---------- per-node gather + ReLU + fused add-pool ----------
__global__ void gather_kernel(const float* __restrict__ H, const int* __restrict__ offsets,
                              const int* __restrict__ csr, const int* __restrict__ batch,
                              float* __restrict__ Xout, float* __restrict__ pool) {
    int tid = blockIdx.x * blockDim.x + threadIdx.x;
    int lane = tid & 63;
    int gw = tid >> 6;
    int nw = (gridDim.x * blockDim.x) >> 6;
    for (int n = gw; n < NN; n += nw) {
        int beg = offsets[n], end = offsets[n + 1];
        float a0 = 0.f, a1 = 0.f, a2 = 0.f, a3 = 0.f;
        int i = beg;
        for (; i + 4 <= end; i += 4) {
            int s0 = csr[i], s1 = csr[i + 1], s2 = csr[i + 2], s3 = csr[i + 3];
            a0 += H[(size_t)s0 * 64 + lane];
            a1 += H[(size_t)s1 * 64 + lane];
            a2 += H[(size_t)s2 * 64 + lane];
            a3 += H[(size_t)s3 * 64 + lane];
        }
        for (; i < end; ++i) a0 += H[(size_t)csr[i] * 64 + lane];
        float v = fmaxf((a0 + a1) + (a2 + a3), 0.f);
        Xout[(size_t)n * 64 + lane] = v;
        unsafeAtomicAdd(&pool[(size_t)batch[n] * 64 + lane], v);
    }
}

// ---------- out[g] = relu(sum_l pool_l[g] @ Wp_l) ----------
__global__ void final_kernel(const float* __restrict__ P1, const float* __restrict__ P2,
                             const float* __restrict__ P3,
                             const float* __restrict__ Wp1, const float* __restrict__ Wp2,
                             const float* __restrict__ Wp3, float* __restrict__ out) {
    int g = blockIdx.x;
    int c = threadIdx.x;  // 64
    float acc = 0.f;
#pragma unroll
    for (int k = 0; k < 64; ++k) {
        acc = fmaf(P1[g * 64 + k], Wp1[k * 64 + c], acc);
        acc = fmaf(P2[g * 64 + k], Wp2[k * 64 + c], acc);
        acc = fmaf(P3[g * 64 + k], Wp3[k * 64 + c], acc);
    }
    out[g * 64 + c] = fmaxf(acc, 0.f);
}

extern "C" void kernel_launch(void* const* d_in, const int* in_sizes, int n_in,
                              void* d_out, int out_size, void* d_ws, size_t ws_size,
                              hipStream_t stream) {
    const float* x     = (const float*)d_in[0];
    const int*   eidx  = (const int*)d_in[1];   // [2, NE]
    const int*   batch = (const int*)d_in[2];   // [NN], sorted
    const float* W1  = (const float*)d_in[3];
    const float* W2  = (const float*)d_in[4];
    const float* W3  = (const float*)d_in[5];
    const float* Wp1 = (const float*)d_in[6];
    const float* Wp2 = (const float*)d_in[7];
    const float* Wp3 = (const float*)d_in[8];
    float* out = (float*)d_out;

    const int* src = eidx;
    const int* dst = eidx + NE;

    // ---- workspace layout ----
    float* bufA  = (float*)d_ws;                        // H      (12.8 MB)
    float* bufB  = bufA + (size_t)NN * DIM;             // x_l    (12.8 MB)
    float* pool1 = bufB + (size_t)NN * DIM;             // 64 KB
    float* pool2 = pool1 + (size_t)NG * DIM;
    float* pool3 = pool2 + (size_t)NG * DIM;
    int* count    = (int*)(pool3 + (size_t)NG * DIM);   // NN
    int* offsets  = count + NN;                          // NN+1
    int* cursor   = offsets + (NN + 1);                  // NN
    int* blocksum = cursor + NN;                         // 256
    int* csr      = blocksum + 256;                      // NE (4 MB)

    hipMemsetAsync(pool1, 0, (size_t)3 * NG * DIM * sizeof(float), stream);
    hipMemsetAsync(count, 0, (size_t)NN * sizeof(int), stream);

    dim3 blk(256);
    // ---- build CSR (by dst) once; reused by all 3 layers ----
    hist_kernel<<<2048, blk, 0, stream>>>(dst, count);
    scanA_kernel<<<NB_SCAN, 256, 0, stream>>>(count, blocksum);
    scanB_kernel<<<1, 256, 0, stream>>>(blocksum);
    scanC_kernel<<<NB_SCAN, 256, 0, stream>>>(count, blocksum, offsets, cursor);
    fill_kernel<<<2048, blk, 0, stream>>>(src, dst, cursor, csr);

    const int gemm_blocks = (NN + 127) / 128;   // 391
    const int gath_blocks = 2048;               // 8192 waves, ~6 nodes each

    const float* xin = x;
    const float* Ws[3]   = {W1, W2, W3};
    float* pools[3] = {pool1, pool2, pool3};
    for (int l = 0; l < 3; ++l) {
        gemm64_kernel<<<gemm_blocks, 128, 0, stream>>>(xin, Ws[l], bufA, NN);
        gather_kernel<<<gath_blocks, blk, 0, stream>>>(bufA, offsets, csr, batch, bufB, pools[l]);
        xin = bufB;
    }
    final_kernel<<<NG, 64, 0, stream>>>(pool1, pool2, pool3, Wp1, Wp2, Wp3, out);
}